// Round 4
// baseline (352.344 us; speedup 1.0000x reference)
//
#include <hip/hip_runtime.h>
#include <hip/hip_bf16.h>

#define M_DIM 16384
#define N_DIM 1000
#define N_PAD 1024
#define K_DIM 2048
#define INV_F (1.0f / 2048.0f)

#define BM 256
#define BN 256
#define BK 64
#define NT (K_DIM / BK)          // 32 K-tiles
#define A_E (BM * BK)            // 16384 elements (32 KB)
#define SLOT_E (2 * A_E)         // A + B per buffer: 32768 elements (64 KB)

typedef __bf16 bf16v8 __attribute__((ext_vector_type(8)));
typedef float  f32v4  __attribute__((ext_vector_type(4)));
typedef unsigned int u32;

__device__ __forceinline__ void gload_lds16(const void* g, void* l) {
  __builtin_amdgcn_global_load_lds(
      (const __attribute__((address_space(1))) u32*)g,
      (__attribute__((address_space(3))) u32*)l, 16, 0, 0);
}

// ---------------------------------------------------------------------------
// fp32 row -> bf16 row + fp32 sum-of-squares. One wave per row, no LDS/syncs.
// Rows >= nvalid zeroed (w padding; d_ws is re-poisoned 0xAA every launch).
// ---------------------------------------------------------------------------
__global__ __launch_bounds__(256) void cvt_rows(
    const float* __restrict__ src, __bf16* __restrict__ dst,
    float* __restrict__ sq, int nvalid)
{
  const int row  = blockIdx.x * 4 + (threadIdx.x >> 6);
  const int lane = threadIdx.x & 63;
  const float4* sr = (const float4*)(src + (size_t)row * K_DIM);
  bf16v8* dr = (bf16v8*)(dst + (size_t)row * K_DIM);
  float s = 0.0f;
  if (row < nvalid) {
    #pragma unroll
    for (int i = 0; i < 4; ++i) {
      float4 a = sr[2 * lane + i * 128];
      float4 b = sr[2 * lane + 1 + i * 128];
      s += a.x*a.x + a.y*a.y + a.z*a.z + a.w*a.w
         + b.x*b.x + b.y*b.y + b.z*b.z + b.w*b.w;
      bf16v8 o;
      o[0]=(__bf16)a.x; o[1]=(__bf16)a.y; o[2]=(__bf16)a.z; o[3]=(__bf16)a.w;
      o[4]=(__bf16)b.x; o[5]=(__bf16)b.y; o[6]=(__bf16)b.z; o[7]=(__bf16)b.w;
      dr[lane + i * 64] = o;
    }
  } else {
    bf16v8 z;
    #pragma unroll
    for (int k = 0; k < 8; ++k) z[k] = (__bf16)0.0f;
    #pragma unroll
    for (int i = 0; i < 4; ++i) dr[lane + i * 64] = z;
  }
  #pragma unroll
  for (int off = 32; off > 0; off >>= 1) s += __shfl_down(s, off, 64);
  if (lane == 0) sq[row] = s;
}

// ---------------------------------------------------------------------------
// 256x256 bf16 MFMA GEMM, BK=64, K-MAJOR LDS (conflict-free), 2 buffers
// (128 KB), 2 phases/tile, counted vmcnt(4), setprio around MFMA.
//
// LDS layout per matrix: chunk (q, r) at element (q*256 + r)*8, where
// q = k-chunk (8 bf16 = 16B), r = tile row. Fragment ds_read_b128 for rows
// {.. + lr} lands on bank slot 4*(lr&7): 8 slots x 8 lanes = the 8-pass
// minimum -> zero bank conflict, no swizzle needed (both-sides-or-neither
// trivially satisfied).
//
// Per tile t (buf p = t&1), phase s in {0,1} (k-half q in {4s..4s+3}):
//   ds_read 12 frags (half s)  |  issue 4 gloads: tile t+1 half s -> buf p^1
//   setprio(1) 32 MFMA setprio(0)
//   s_waitcnt vmcnt(4)   // my half-(s+1) loads landed; newest 4 stay in flight
//   s_barrier            // cross-wave: ALL waves' loads for that half landed
// WAR: staging half s of t+1 overwrites chunks last read in phase s of t-1,
// separated by two barriers. RAW: vmcnt precedes the barrier (m201 pattern).
// ---------------------------------------------------------------------------
__global__ __launch_bounds__(512, 2) void gemm_ep(
    const __bf16* __restrict__ A, const __bf16* __restrict__ B,
    const float* __restrict__ x2, const float* __restrict__ w2,
    float* __restrict__ out)
{
  __shared__ __bf16 lds[2 * SLOT_E];   // 128 KB

  // T1: bijective XCD swizzle (256 blocks, 8 XCDs): each XCD owns 8 A-panels.
  const int bid = blockIdx.x;
  const int swz = (bid & 7) * 32 + (bid >> 3);
  const int bm = swz >> 2;          // 64 row tiles
  const int bn = swz & 3;           // 4 col tiles, fastest (A-panel reuse)
  const int brow = bm * BM;
  const int bcol = bn * BN;

  const int tid  = threadIdx.x;
  const int lane = tid & 63;
  const int wid  = tid >> 6;
  const int wm   = wid >> 2;        // 0..1
  const int wn   = wid & 3;         // 0..3

  // staging sources: chunk c = i*512 + tid  ->  q = c>>8, r = c&255.
  // i in {0,1} = K-half 0 (q 0..3), i in {2,3} = K-half 1 (q 4..7).
  const __bf16* gA[4];
  const __bf16* gB[4];
  #pragma unroll
  for (int i = 0; i < 4; ++i) {
    const int c = i * 512 + tid;
    const int r = c & 255;
    const int q = c >> 8;
    gA[i] = A + (size_t)(brow + r) * K_DIM + q * 8;
    gB[i] = B + (size_t)(bcol + r) * K_DIM + q * 8;
  }

  f32v4 acc[8][4];
  #pragma unroll
  for (int m = 0; m < 8; ++m)
    #pragma unroll
    for (int n = 0; n < 4; ++n)
      acc[m][n] = (f32v4){0.f, 0.f, 0.f, 0.f};

  const int lr = lane & 15;
  const int g  = lane >> 4;
  // fragment element offsets (K-major): (q*256 + row)*8, q = s*4 + g
  const int aBase = g * 2048 + (wm * 128 + lr) * 8;          // + s*8192 + m*128
  const int bBase = A_E + g * 2048 + (wn * 64 + lr) * 8;     // + s*8192 + n*128

#define ISSUE_HALF(kt, h, nb)                                        \
  do {                                                               \
    const int _ko = (kt) * BK;                                       \
    _Pragma("unroll")                                                \
    for (int _i = 2 * (h); _i < 2 * (h) + 2; ++_i) {                 \
      gload_lds16(gA[_i] + _ko, (nb) + (_i * 512 + tid) * 8);        \
      gload_lds16(gB[_i] + _ko, (nb) + A_E + (_i * 512 + tid) * 8);  \
    }                                                                \
  } while (0)

  // prologue: stage tile 0 (both halves); half-0 landed for all waves.
  ISSUE_HALF(0, 0, lds);
  ISSUE_HALF(0, 1, lds);
  asm volatile("s_waitcnt vmcnt(4)" ::: "memory");
  __builtin_amdgcn_s_barrier();
  asm volatile("" ::: "memory");

  #pragma unroll 1
  for (int t = 0; t < NT; ++t) {
    const int p = t & 1;
    const __bf16* sb = lds + p * SLOT_E;
    __bf16* nb = lds + (p ^ 1) * SLOT_E;
    const bool more = (t + 1 < NT);

    #pragma unroll
    for (int s = 0; s < 2; ++s) {
      bf16v8 a[8], b[4];
      #pragma unroll
      for (int m = 0; m < 8; ++m)
        a[m] = *(const bf16v8*)(sb + aBase + s * 8192 + m * 128);
      #pragma unroll
      for (int n = 0; n < 4; ++n)
        b[n] = *(const bf16v8*)(sb + bBase + s * 8192 + n * 128);

      if (more) ISSUE_HALF(t + 1, s, nb);

      __builtin_amdgcn_s_setprio(1);
      #pragma unroll
      for (int m = 0; m < 8; ++m)
        #pragma unroll
        for (int n = 0; n < 4; ++n)
          acc[m][n] = __builtin_amdgcn_mfma_f32_16x16x32_bf16(a[m], b[n], acc[m][n], 0, 0, 0);
      __builtin_amdgcn_s_setprio(0);

      if (s == 0) {
        if (more) asm volatile("s_waitcnt vmcnt(4)" ::: "memory");
        else      asm volatile("s_waitcnt vmcnt(0)" ::: "memory");
        __builtin_amdgcn_s_barrier();
        asm volatile("" ::: "memory");
      } else if (more) {
        asm volatile("s_waitcnt vmcnt(4)" ::: "memory");
        __builtin_amdgcn_s_barrier();
        asm volatile("" ::: "memory");
      }
    }
  }
#undef ISSUE_HALF

  // epilogue: C/D layout col = lane&15, row = (lane>>4)*4 + j  (m89/m91)
  const int r0 = brow + wm * 128 + (lane >> 4) * 4;
  const int c0 = bcol + wn * 64 + lr;
  #pragma unroll
  for (int m = 0; m < 8; ++m) {
    const int row = r0 + m * 16;
    float xr[4];
    #pragma unroll
    for (int j = 0; j < 4; ++j) xr[j] = x2[row + j];
    #pragma unroll
    for (int n = 0; n < 4; ++n) {
      const int col = c0 + n * 16;
      if (col < N_DIM) {
        const float w2c = w2[col];
        #pragma unroll
        for (int j = 0; j < 4; ++j)
          out[(size_t)(row + j) * N_DIM + col] =
              (2.0f * acc[m][n][j] - xr[j] - w2c) * INV_F;
      }
    }
  }
}

// ---------------------------------------------------------------------------
// Safety net if ws_size is too small: direct fp32 computation.
// ---------------------------------------------------------------------------
__global__ __launch_bounds__(256) void fallback_fp32(
    const float* __restrict__ x, const float* __restrict__ w,
    float* __restrict__ out)
{
  long idx = (long)blockIdx.x * 256 + threadIdx.x;
  if (idx >= (long)M_DIM * N_DIM) return;
  int row = (int)(idx / N_DIM);
  int col = (int)(idx % N_DIM);
  const float4* xr = (const float4*)(x + (size_t)row * K_DIM);
  const float4* wr = (const float4*)(w + (size_t)col * K_DIM);
  float s = 0.f;
  for (int i = 0; i < K_DIM / 4; ++i) {
    float4 a = xr[i], b = wr[i];
    float d0 = a.x - b.x, d1 = a.y - b.y, d2 = a.z - b.z, d3 = a.w - b.w;
    s += d0*d0 + d1*d1 + d2*d2 + d3*d3;
  }
  out[idx] = -s * INV_F;
}

extern "C" void kernel_launch(void* const* d_in, const int* in_sizes, int n_in,
                              void* d_out, int out_size, void* d_ws, size_t ws_size,
                              hipStream_t stream) {
  const float* x = (const float*)d_in[0];
  const float* w = (const float*)d_in[1];
  float* out = (float*)d_out;

  const size_t need = (size_t)M_DIM * K_DIM * 2
                    + (size_t)N_PAD * K_DIM * 2
                    + (size_t)M_DIM * 4
                    + (size_t)N_PAD * 4;
  if (ws_size < need) {
    const long total = (long)M_DIM * N_DIM;
    fallback_fp32<<<(int)((total + 255) / 256), 256, 0, stream>>>(x, w, out);
    return;
  }

  __bf16* xb = (__bf16*)d_ws;
  __bf16* wb = xb + (size_t)M_DIM * K_DIM;
  float* x2 = (float*)(wb + (size_t)N_PAD * K_DIM);
  float* w2 = x2 + M_DIM;

  cvt_rows<<<M_DIM / 4, 256, 0, stream>>>(x, xb, x2, M_DIM);
  cvt_rows<<<N_PAD / 4, 256, 0, stream>>>(w, wb, w2, N_DIM);
  gemm_ep<<<(M_DIM / BM) * (N_PAD / BN), 512, 0, stream>>>(xb, wb, x2, w2, out);
}

// Round 5
// 284.784 us; speedup vs baseline: 1.2372x; 1.2372x over previous
//
#include <hip/hip_runtime.h>
#include <hip/hip_bf16.h>

#define M_DIM 16384
#define N_DIM 1000
#define N_PAD 1024
#define K_DIM 2048
#define INV_F (1.0f / 2048.0f)

#define BM 256
#define BN 256
#define BK 32
#define NT (K_DIM / BK)            // 64 K-steps
#define SLOT_ELEMS (2 * BM * BK)   // A + B per ring slot, bf16 elements (16384)

typedef __bf16 bf16v8 __attribute__((ext_vector_type(8)));
typedef float  f32v4  __attribute__((ext_vector_type(4)));
typedef unsigned int u32;

// async global->LDS, 16B per lane (width=16 fast path, m97)
__device__ __forceinline__ void gload_lds16(const void* g, void* l) {
  __builtin_amdgcn_global_load_lds(
      (const __attribute__((address_space(1))) u32*)g,
      (__attribute__((address_space(3))) u32*)l, 16, 0, 0);
}

// ---------------------------------------------------------------------------
// fp32 row -> bf16 row + fp32 sum-of-squares. One wave per row, no LDS/syncs.
// Rows >= nvalid zeroed (w padding; d_ws is re-poisoned 0xAA every launch).
// ---------------------------------------------------------------------------
__global__ __launch_bounds__(256) void cvt_rows(
    const float* __restrict__ src, __bf16* __restrict__ dst,
    float* __restrict__ sq, int nvalid)
{
  const int row  = blockIdx.x * 4 + (threadIdx.x >> 6);
  const int lane = threadIdx.x & 63;
  const float4* sr = (const float4*)(src + (size_t)row * K_DIM);
  bf16v8* dr = (bf16v8*)(dst + (size_t)row * K_DIM);
  float s = 0.0f;
  if (row < nvalid) {
    #pragma unroll
    for (int i = 0; i < 4; ++i) {
      float4 a = sr[2 * lane + i * 128];
      float4 b = sr[2 * lane + 1 + i * 128];
      s += a.x*a.x + a.y*a.y + a.z*a.z + a.w*a.w
         + b.x*b.x + b.y*b.y + b.z*b.z + b.w*b.w;
      bf16v8 o;
      o[0]=(__bf16)a.x; o[1]=(__bf16)a.y; o[2]=(__bf16)a.z; o[3]=(__bf16)a.w;
      o[4]=(__bf16)b.x; o[5]=(__bf16)b.y; o[6]=(__bf16)b.z; o[7]=(__bf16)b.w;
      dr[lane + i * 64] = o;
    }
  } else {
    bf16v8 z;
    #pragma unroll
    for (int k = 0; k < 8; ++k) z[k] = (__bf16)0.0f;
    #pragma unroll
    for (int i = 0; i < 4; ++i) dr[lane + i * 64] = z;
  }
  #pragma unroll
  for (int off = 32; off > 0; off >>= 1) s += __shfl_down(s, off, 64);
  if (lane == 0) sq[row] = s;
}

// ---------------------------------------------------------------------------
// 256x256 bf16 MFMA GEMM, BK=32, 3-slot LDS ring (96 KB), counted vmcnt(4)
// (round-3 structure, 82.9 us) + T2 both-sides XOR swizzle (the ONE change):
//
//   LDS holds 16B chunks; chunk (q = k-group 0..3, r = tile row) stored at
//   position p = r*4 + (q ^ ((r>>1)&3)).
//   - staging: LDS dest stays LINEAR (gload_lds contract, m104); the global
//     SOURCE is inverse-permuted: lane covering position c reads column
//     chunk q = (c&3) ^ ((c>>3)&3) of row c>>2. Identical q for c and c+512,
//     and each row's 64B is still covered by 4 lanes -> coalescing kept.
//   - read: fragment (row, g) lives at element row*BK + (g ^ ((lr>>1)&3))*8;
//     m*16 / wm*128 / wn*64 are 0 mod 8 rows, so the XOR is a per-lane
//     constant (lkx) -- zero runtime cost vs round 3.
//   Bank check: each 16-lane g-group hits all 8 four-bank slots with 2-way
//   aliasing only (free, m136) -> conflict-free ds_read_b128.
//
// Ring discipline per K-step t (reading slot t%3): issue 4 gloads for tile
// t+2 into slot (t+2)%3; ds_read + 32 MFMA; lgkmcnt(0)+sched_barrier (rule
// #18); vmcnt(4) [t+1 landed, t+2 in flight -- never 0 in main loop]; raw
// s_barrier. Epilogue fuses out = (2*acc - x2[r] - w2[c])/F, guard c<1000.
// ---------------------------------------------------------------------------
__global__ __launch_bounds__(512, 2) void gemm_ep(
    const __bf16* __restrict__ A, const __bf16* __restrict__ B,
    const float* __restrict__ x2, const float* __restrict__ w2,
    float* __restrict__ out)
{
  __shared__ __bf16 lds[3 * SLOT_ELEMS];   // 96 KB

  // T1: bijective XCD swizzle (256 blocks % 8 == 0): each XCD owns 8 A-panels.
  const int bid = blockIdx.x;
  const int swz = (bid & 7) * 32 + (bid >> 3);
  const int bm = swz >> 2;          // 64 row tiles
  const int bn = swz & 3;           // 4 col tiles, fastest (A-panel reuse)
  const int brow = bm * BM;
  const int bcol = bn * BN;

  const int tid  = threadIdx.x;
  const int lane = tid & 63;
  const int wid  = tid >> 6;
  const int wm   = wid >> 2;        // 0..1
  const int wn   = wid & 3;         // 0..3

  // staging source: position c=tid covers row tid>>2; SWIZZLED column chunk
  const int srow = tid >> 2;
  const int scol = (((tid & 3) ^ ((tid >> 3) & 3))) * 8;
  const __bf16* gA0 = A + (size_t)(brow + srow) * K_DIM + scol;
  const __bf16* gA1 = gA0 + (size_t)128 * K_DIM;
  const __bf16* gB0 = B + (size_t)(bcol + srow) * K_DIM + scol;
  const __bf16* gB1 = gB0 + (size_t)128 * K_DIM;

  // staging dest element offsets within a slot (linear: uniform base + lane*16B)
  const int dA0 = tid * 8;
  const int dA1 = (512 + tid) * 8;
  const int dB0 = BM * BK + tid * 8;
  const int dB1 = BM * BK + (512 + tid) * 8;

  f32v4 acc[8][4];
  #pragma unroll
  for (int m = 0; m < 8; ++m)
    #pragma unroll
    for (int n = 0; n < 4; ++n)
      acc[m][n] = (f32v4){0.f, 0.f, 0.f, 0.f};

  const int lr = lane & 15;
  const int g  = lane >> 4;
  // swizzled k-group offset: fetches true chunk q=g from its permuted slot
  const int lkx = (g ^ ((lr >> 1) & 3)) * 8;
  const int aOff = (wm * 128 + lr) * BK + lkx;            // + m*16*BK
  const int bOff = BM * BK + (wn * 64 + lr) * BK + lkx;   // + n*16*BK

  // prologue: stage tiles 0 and 1; wait tile 0 (vmcnt(4): tile 1 in flight)
  {
    __bf16* s0 = lds;
    gload_lds16(gA0, s0 + dA0); gload_lds16(gA1, s0 + dA1);
    gload_lds16(gB0, s0 + dB0); gload_lds16(gB1, s0 + dB1);
    __bf16* s1 = lds + SLOT_ELEMS;
    gload_lds16(gA0 + BK, s1 + dA0); gload_lds16(gA1 + BK, s1 + dA1);
    gload_lds16(gB0 + BK, s1 + dB0); gload_lds16(gB1 + BK, s1 + dB1);
  }
  asm volatile("s_waitcnt vmcnt(4)" ::: "memory");
  __builtin_amdgcn_s_barrier();
  asm volatile("" ::: "memory");

  int slot = 0;
  #pragma unroll 1
  for (int t = 0; t < NT; ++t) {
    if (t + 2 < NT) {
      int s2 = slot + 2; if (s2 >= 3) s2 -= 3;
      __bf16* sb = lds + s2 * SLOT_ELEMS;
      const int ko = (t + 2) * BK;
      gload_lds16(gA0 + ko, sb + dA0);
      gload_lds16(gA1 + ko, sb + dA1);
      gload_lds16(gB0 + ko, sb + dB0);
      gload_lds16(gB1 + ko, sb + dB1);
    }

    const __bf16* sb = lds + slot * SLOT_ELEMS;
    bf16v8 a[8], b[4];
    #pragma unroll
    for (int m = 0; m < 8; ++m)
      a[m] = *(const bf16v8*)(sb + aOff + m * 16 * BK);
    #pragma unroll
    for (int n = 0; n < 4; ++n)
      b[n] = *(const bf16v8*)(sb + bOff + n * 16 * BK);

    #pragma unroll
    for (int m = 0; m < 8; ++m)
      #pragma unroll
      for (int n = 0; n < 4; ++n)
        acc[m][n] = __builtin_amdgcn_mfma_f32_16x16x32_bf16(a[m], b[n], acc[m][n], 0, 0, 0);

    // WAR: all my LDS reads drained before crossing the barrier
    asm volatile("s_waitcnt lgkmcnt(0)" ::: "memory");
    __builtin_amdgcn_sched_barrier(0);
    // RAW: tile t+1's loads (mine) landed; tile t+2's stay in flight
    if (t + 2 < NT) asm volatile("s_waitcnt vmcnt(4)" ::: "memory");
    else            asm volatile("s_waitcnt vmcnt(0)" ::: "memory");
    __builtin_amdgcn_s_barrier();
    asm volatile("" ::: "memory");

    slot = (slot == 2) ? 0 : slot + 1;
  }

  // epilogue: C/D layout col = lane&15, row = (lane>>4)*4 + j  (m89/m91)
  const int r0 = brow + wm * 128 + (lane >> 4) * 4;
  const int c0 = bcol + wn * 64 + lr;
  #pragma unroll
  for (int m = 0; m < 8; ++m) {
    const int row = r0 + m * 16;
    float xr[4];
    #pragma unroll
    for (int j = 0; j < 4; ++j) xr[j] = x2[row + j];
    #pragma unroll
    for (int n = 0; n < 4; ++n) {
      const int col = c0 + n * 16;
      if (col < N_DIM) {
        const float w2c = w2[col];
        #pragma unroll
        for (int j = 0; j < 4; ++j)
          out[(size_t)(row + j) * N_DIM + col] =
              (2.0f * acc[m][n][j] - xr[j] - w2c) * INV_F;
      }
    }
  }
}

// ---------------------------------------------------------------------------
// Safety net if ws_size is too small: direct fp32 computation.
// ---------------------------------------------------------------------------
__global__ __launch_bounds__(256) void fallback_fp32(
    const float* __restrict__ x, const float* __restrict__ w,
    float* __restrict__ out)
{
  long idx = (long)blockIdx.x * 256 + threadIdx.x;
  if (idx >= (long)M_DIM * N_DIM) return;
  int row = (int)(idx / N_DIM);
  int col = (int)(idx % N_DIM);
  const float4* xr = (const float4*)(x + (size_t)row * K_DIM);
  const float4* wr = (const float4*)(w + (size_t)col * K_DIM);
  float s = 0.f;
  for (int i = 0; i < K_DIM / 4; ++i) {
    float4 a = xr[i], b = wr[i];
    float d0 = a.x - b.x, d1 = a.y - b.y, d2 = a.z - b.z, d3 = a.w - b.w;
    s += d0*d0 + d1*d1 + d2*d2 + d3*d3;
  }
  out[idx] = -s * INV_F;
}

extern "C" void kernel_launch(void* const* d_in, const int* in_sizes, int n_in,
                              void* d_out, int out_size, void* d_ws, size_t ws_size,
                              hipStream_t stream) {
  const float* x = (const float*)d_in[0];
  const float* w = (const float*)d_in[1];
  float* out = (float*)d_out;

  const size_t need = (size_t)M_DIM * K_DIM * 2
                    + (size_t)N_PAD * K_DIM * 2
                    + (size_t)M_DIM * 4
                    + (size_t)N_PAD * 4;
  if (ws_size < need) {
    const long total = (long)M_DIM * N_DIM;
    fallback_fp32<<<(int)((total + 255) / 256), 256, 0, stream>>>(x, w, out);
    return;
  }

  __bf16* xb = (__bf16*)d_ws;
  __bf16* wb = xb + (size_t)M_DIM * K_DIM;
  float* x2 = (float*)(wb + (size_t)N_PAD * K_DIM);
  float* w2 = x2 + M_DIM;

  cvt_rows<<<M_DIM / 4, 256, 0, stream>>>(x, xb, x2, M_DIM);
  cvt_rows<<<N_PAD / 4, 256, 0, stream>>>(w, wb, w2, N_DIM);
  gemm_ep<<<(M_DIM / BM) * (N_PAD / BN), 512, 0, stream>>>(xb, wb, x2, w2, out);
}

// Round 6
// 278.104 us; speedup vs baseline: 1.2670x; 1.0240x over previous
//
#include <hip/hip_runtime.h>
#include <hip/hip_bf16.h>

#define M_DIM 16384
#define N_DIM 1000
#define N_PAD 1024
#define K_DIM 2048
#define INV_F (1.0f / 2048.0f)

#define BM 256
#define BN 256
#define BK 64
#define NT (K_DIM / BK)          // 32 K-tiles
#define A_E (BM * BK)            // 16384 elems = 32 KB per matrix per buf
#define SLOT_E (2 * A_E)         // A+B per buf = 64 KB

typedef __bf16 bf16v8 __attribute__((ext_vector_type(8)));
typedef float  f32v4  __attribute__((ext_vector_type(4)));
typedef unsigned int u32;

__device__ __forceinline__ void gload_lds16(const void* g, void* l) {
  __builtin_amdgcn_global_load_lds(
      (const __attribute__((address_space(1))) u32*)g,
      (__attribute__((address_space(3))) u32*)l, 16, 0, 0);
}

// ---------------------------------------------------------------------------
// fp32 row -> bf16 row + fp32 sum-of-squares. One wave per row, no LDS/syncs.
// Rows >= nvalid zeroed (w padding; d_ws is re-poisoned 0xAA every launch).
// ---------------------------------------------------------------------------
__global__ __launch_bounds__(256) void cvt_rows(
    const float* __restrict__ src, __bf16* __restrict__ dst,
    float* __restrict__ sq, int nvalid)
{
  const int row  = blockIdx.x * 4 + (threadIdx.x >> 6);
  const int lane = threadIdx.x & 63;
  const float4* sr = (const float4*)(src + (size_t)row * K_DIM);
  bf16v8* dr = (bf16v8*)(dst + (size_t)row * K_DIM);
  float s = 0.0f;
  if (row < nvalid) {
    #pragma unroll
    for (int i = 0; i < 4; ++i) {
      float4 a = sr[2 * lane + i * 128];
      float4 b = sr[2 * lane + 1 + i * 128];
      s += a.x*a.x + a.y*a.y + a.z*a.z + a.w*a.w
         + b.x*b.x + b.y*b.y + b.z*b.z + b.w*b.w;
      bf16v8 o;
      o[0]=(__bf16)a.x; o[1]=(__bf16)a.y; o[2]=(__bf16)a.z; o[3]=(__bf16)a.w;
      o[4]=(__bf16)b.x; o[5]=(__bf16)b.y; o[6]=(__bf16)b.z; o[7]=(__bf16)b.w;
      dr[lane + i * 64] = o;
    }
  } else {
    bf16v8 z;
    #pragma unroll
    for (int k = 0; k < 8; ++k) z[k] = (__bf16)0.0f;
    #pragma unroll
    for (int i = 0; i < 4; ++i) dr[lane + i * 64] = z;
  }
  #pragma unroll
  for (int off = 32; off > 0; off >>= 1) s += __shfl_down(s, off, 64);
  if (lane == 0) sq[row] = s;
}

// ---------------------------------------------------------------------------
// 256x256 bf16 MFMA GEMM, BK=64, 4-phase/K-tile schedule (T3+T4+T5), 2 LDS
// bufs (128 KB), 8 waves (2M x 4N), per-wave 128x64 = 8x4 frags 16x16x32.
//
// LDS layout per matrix: [256 rows][8 slots of 16B]; chunk c (=k-group 0..7)
// of row r stored at slot c ^ (r&7)  -> frag reads conflict-free (start banks
// (c^(lr&7))*4 cover all 32 banks per 8 lanes, 2-way alias = free).
// Staging keeps LINEAR per-wave dest (base+lane*16, gload_lds contract); the
// global SOURCE is inverse-permuted within each row's 128B segment
// (coalescing intact).
//
// Consumption-aligned half-tiles (so counted vmcnt(4) = 2 half-tiles in
// flight suffices, never 0 in steady state):
//   A-H1 = rows {0-63,128-191} (each wave-m-half's first 64 rows), A-H2 rest
//   B-H1 = rows {0-31,64-95,128-159,192-223} (first n-half per wave), B-H2 rest
// Stage order per tile: A1,B1,B2,A2. Phase p reads: p1:{A1,B1} p2:{B2}
// p3:{A2} p4:{}. Queue evolution (2 loads/half-tile, wait at each phase end):
//   end p1 {B2,A2,A1'}->vmcnt(4)->B2 landed; end p2 {A2,A1',B1'}->A2 landed;
//   end p3 -> A1' landed; end p4 {B1',B2',A2'}->vmcnt(4)->A1',B1' landed
//   = exactly what the next phase reads. Last tile: vmcnt(2) / vmcnt(0).
// WAR: region overwritten >=3 barriers after its reads drained (per-phase
// lgkmcnt(0)). ds_reads sit BEFORE each barrier -> overlap other waves' MFMA
// (the LDS-unit || MFMA-pipe overlap that round 5's lockstep lacked).
// ---------------------------------------------------------------------------
__global__ __launch_bounds__(512, 2) void gemm_ep(
    const __bf16* __restrict__ A, const __bf16* __restrict__ B,
    const float* __restrict__ x2, const float* __restrict__ w2,
    float* __restrict__ out)
{
  __shared__ __bf16 lds[2 * SLOT_E];   // 128 KB

  // T1: bijective XCD swizzle (256 blocks % 8 == 0): each XCD owns 8 A-panels.
  const int bid = blockIdx.x;
  const int swz = (bid & 7) * 32 + (bid >> 3);
  const int bm = swz >> 2;          // 64 row tiles
  const int bn = swz & 3;           // 4 col tiles, fastest (A-panel reuse)
  const int brow = bm * BM;
  const int bcol = bn * BN;

  const int tid  = threadIdx.x;
  const int lane = tid & 63;
  const int wid  = tid >> 6;
  const int wm   = wid >> 2;        // 0..1
  const int wn   = wid & 3;         // 0..3

  // ---- staging geometry: per half-tile, 2 loads/thread (l=0,1) ----
  const __bf16* srcA[4]; const __bf16* srcB[4];
  int dstA[4], dstB[4];
  #pragma unroll
  for (int h = 0; h < 2; ++h)
    #pragma unroll
    for (int l = 0; l < 2; ++l) {
      const int i = l * 512 + tid;
      const int p = i >> 3;         // 0..127 within half-tile
      const int slot = i & 7;
      const int rowA = ((p < 64) ? p : p + 64) + h * 64;   // H1:{0-63,128-191}
      srcA[h*2+l] = A + (size_t)(brow + rowA) * K_DIM + (slot ^ (rowA & 7)) * 8;
      dstA[h*2+l] = rowA * 64 + slot * 8;
      const int rowB = ((p >> 5) * 64 + (p & 31)) + h * 32; // H1: first 32 of each 64-block
      srcB[h*2+l] = B + (size_t)(bcol + rowB) * K_DIM + (slot ^ (rowB & 7)) * 8;
      dstB[h*2+l] = A_E + rowB * 64 + slot * 8;
    }

#define STAGE_A(h, kt, nb) do {                                          \
    gload_lds16(srcA[(h)*2+0] + (size_t)(kt) * BK, (nb) + dstA[(h)*2+0]);\
    gload_lds16(srcA[(h)*2+1] + (size_t)(kt) * BK, (nb) + dstA[(h)*2+1]);\
  } while (0)
#define STAGE_B(h, kt, nb) do {                                          \
    gload_lds16(srcB[(h)*2+0] + (size_t)(kt) * BK, (nb) + dstB[(h)*2+0]);\
    gload_lds16(srcB[(h)*2+1] + (size_t)(kt) * BK, (nb) + dstB[(h)*2+1]);\
  } while (0)

  // ---- fragment read offsets (swizzled, per-lane constant) ----
  const int lr = lane & 15;
  const int g  = lane >> 4;
  const int lkx[2] = { ((0 + g) ^ (lr & 7)) * 8, ((4 + g) ^ (lr & 7)) * 8 };
  const int aBase = (wm * 128 + lr) * 64;          // + m*1024 + lkx[s]
  const int bBase = A_E + (wn * 64 + lr) * 64;     // + n*1024 + lkx[s]

  f32v4 acc[8][4];
  #pragma unroll
  for (int m = 0; m < 8; ++m)
    #pragma unroll
    for (int n = 0; n < 4; ++n)
      acc[m][n] = (f32v4){0.f, 0.f, 0.f, 0.f};

  bf16v8 a[4][2], b[4][2];

  // ---- prologue: stage tile 0 in order A1,B1,B2,A2; A1,B1 landed ----
  STAGE_A(0, 0, (__bf16*)lds);
  STAGE_B(0, 0, (__bf16*)lds);
  STAGE_B(1, 0, (__bf16*)lds);
  STAGE_A(1, 0, (__bf16*)lds);
  asm volatile("s_waitcnt vmcnt(4)" ::: "memory");
  __builtin_amdgcn_s_barrier();
  asm volatile("" ::: "memory");

  #pragma unroll 1
  for (int t = 0; t < NT; ++t) {
    const __bf16* cur = (const __bf16*)lds + (t & 1) * SLOT_E;
    __bf16* nxt = (__bf16*)lds + ((t & 1) ^ 1) * SLOT_E;
    const bool more = (t + 1 < NT);

    // ================= phase 1: quadrant (m0-3, n0-1) =================
    #pragma unroll
    for (int m = 0; m < 4; ++m)
      #pragma unroll
      for (int s = 0; s < 2; ++s)
        a[m][s] = *(const bf16v8*)(cur + aBase + m * 1024 + lkx[s]);
    #pragma unroll
    for (int n = 0; n < 2; ++n)
      #pragma unroll
      for (int s = 0; s < 2; ++s)
        b[n][s] = *(const bf16v8*)(cur + bBase + n * 1024 + lkx[s]);
    if (more) STAGE_A(0, t + 1, nxt);
    __builtin_amdgcn_sched_barrier(0);
    if (more) asm volatile("s_waitcnt vmcnt(4)" ::: "memory");
    else      asm volatile("s_waitcnt vmcnt(2)" ::: "memory");
    __builtin_amdgcn_s_barrier();
    asm volatile("s_waitcnt lgkmcnt(0)" ::: "memory");
    __builtin_amdgcn_sched_barrier(0);
    __builtin_amdgcn_s_setprio(1);
    #pragma unroll
    for (int m = 0; m < 4; ++m)
      #pragma unroll
      for (int n = 0; n < 2; ++n) {
        acc[m][n] = __builtin_amdgcn_mfma_f32_16x16x32_bf16(a[m][0], b[n][0], acc[m][n], 0, 0, 0);
        acc[m][n] = __builtin_amdgcn_mfma_f32_16x16x32_bf16(a[m][1], b[n][1], acc[m][n], 0, 0, 0);
      }
    __builtin_amdgcn_s_setprio(0);

    // ================= phase 2: quadrant (m0-3, n2-3) =================
    #pragma unroll
    for (int n = 2; n < 4; ++n)
      #pragma unroll
      for (int s = 0; s < 2; ++s)
        b[n][s] = *(const bf16v8*)(cur + bBase + n * 1024 + lkx[s]);
    if (more) STAGE_B(0, t + 1, nxt);
    __builtin_amdgcn_sched_barrier(0);
    if (more) asm volatile("s_waitcnt vmcnt(4)" ::: "memory");
    else      asm volatile("s_waitcnt vmcnt(0)" ::: "memory");
    __builtin_amdgcn_s_barrier();
    asm volatile("s_waitcnt lgkmcnt(0)" ::: "memory");
    __builtin_amdgcn_sched_barrier(0);
    __builtin_amdgcn_s_setprio(1);
    #pragma unroll
    for (int m = 0; m < 4; ++m)
      #pragma unroll
      for (int n = 2; n < 4; ++n) {
        acc[m][n] = __builtin_amdgcn_mfma_f32_16x16x32_bf16(a[m][0], b[n][0], acc[m][n], 0, 0, 0);
        acc[m][n] = __builtin_amdgcn_mfma_f32_16x16x32_bf16(a[m][1], b[n][1], acc[m][n], 0, 0, 0);
      }
    __builtin_amdgcn_s_setprio(0);

    // ================= phase 3: quadrant (m4-7, n0-1) =================
    #pragma unroll
    for (int m = 0; m < 4; ++m)
      #pragma unroll
      for (int s = 0; s < 2; ++s)
        a[m][s] = *(const bf16v8*)(cur + aBase + (4 + m) * 1024 + lkx[s]);
    if (more) STAGE_B(1, t + 1, nxt);
    __builtin_amdgcn_sched_barrier(0);
    if (more) asm volatile("s_waitcnt vmcnt(4)" ::: "memory");
    __builtin_amdgcn_s_barrier();
    asm volatile("s_waitcnt lgkmcnt(0)" ::: "memory");
    __builtin_amdgcn_sched_barrier(0);
    __builtin_amdgcn_s_setprio(1);
    #pragma unroll
    for (int m = 0; m < 4; ++m)
      #pragma unroll
      for (int n = 0; n < 2; ++n) {
        acc[4+m][n] = __builtin_amdgcn_mfma_f32_16x16x32_bf16(a[m][0], b[n][0], acc[4+m][n], 0, 0, 0);
        acc[4+m][n] = __builtin_amdgcn_mfma_f32_16x16x32_bf16(a[m][1], b[n][1], acc[4+m][n], 0, 0, 0);
      }
    __builtin_amdgcn_s_setprio(0);

    // ================= phase 4: quadrant (m4-7, n2-3), no reads =======
    if (more) STAGE_A(1, t + 1, nxt);
    __builtin_amdgcn_sched_barrier(0);
    if (more) asm volatile("s_waitcnt vmcnt(4)" ::: "memory");
    __builtin_amdgcn_s_barrier();
    asm volatile("" ::: "memory");
    __builtin_amdgcn_s_setprio(1);
    #pragma unroll
    for (int m = 0; m < 4; ++m)
      #pragma unroll
      for (int n = 2; n < 4; ++n) {
        acc[4+m][n] = __builtin_amdgcn_mfma_f32_16x16x32_bf16(a[m][0], b[n][0], acc[4+m][n], 0, 0, 0);
        acc[4+m][n] = __builtin_amdgcn_mfma_f32_16x16x32_bf16(a[m][1], b[n][1], acc[4+m][n], 0, 0, 0);
      }
    __builtin_amdgcn_s_setprio(0);
  }
#undef STAGE_A
#undef STAGE_B

  // epilogue: C/D layout col = lane&15, row = (lane>>4)*4 + j  (m89/m91)
  const int r0 = brow + wm * 128 + (lane >> 4) * 4;
  const int c0 = bcol + wn * 64 + lr;
  #pragma unroll
  for (int m = 0; m < 8; ++m) {
    const int row = r0 + m * 16;
    float xr[4];
    #pragma unroll
    for (int j = 0; j < 4; ++j) xr[j] = x2[row + j];
    #pragma unroll
    for (int n = 0; n < 4; ++n) {
      const int col = c0 + n * 16;
      if (col < N_DIM) {
        const float w2c = w2[col];
        #pragma unroll
        for (int j = 0; j < 4; ++j)
          out[(size_t)(row + j) * N_DIM + col] =
              (2.0f * acc[m][n][j] - xr[j] - w2c) * INV_F;
      }
    }
  }
}

// ---------------------------------------------------------------------------
// Safety net if ws_size is too small: direct fp32 computation.
// ---------------------------------------------------------------------------
__global__ __launch_bounds__(256) void fallback_fp32(
    const float* __restrict__ x, const float* __restrict__ w,
    float* __restrict__ out)
{
  long idx = (long)blockIdx.x * 256 + threadIdx.x;
  if (idx >= (long)M_DIM * N_DIM) return;
  int row = (int)(idx / N_DIM);
  int col = (int)(idx % N_DIM);
  const float4* xr = (const float4*)(x + (size_t)row * K_DIM);
  const float4* wr = (const float4*)(w + (size_t)col * K_DIM);
  float s = 0.f;
  for (int i = 0; i < K_DIM / 4; ++i) {
    float4 a = xr[i], b = wr[i];
    float d0 = a.x - b.x, d1 = a.y - b.y, d2 = a.z - b.z, d3 = a.w - b.w;
    s += d0*d0 + d1*d1 + d2*d2 + d3*d3;
  }
  out[idx] = -s * INV_F;
}

extern "C" void kernel_launch(void* const* d_in, const int* in_sizes, int n_in,
                              void* d_out, int out_size, void* d_ws, size_t ws_size,
                              hipStream_t stream) {
  const float* x = (const float*)d_in[0];
  const float* w = (const float*)d_in[1];
  float* out = (float*)d_out;

  const size_t need = (size_t)M_DIM * K_DIM * 2
                    + (size_t)N_PAD * K_DIM * 2
                    + (size_t)M_DIM * 4
                    + (size_t)N_PAD * 4;
  if (ws_size < need) {
    const long total = (long)M_DIM * N_DIM;
    fallback_fp32<<<(int)((total + 255) / 256), 256, 0, stream>>>(x, w, out);
    return;
  }

  __bf16* xb = (__bf16*)d_ws;
  __bf16* wb = xb + (size_t)M_DIM * K_DIM;
  float* x2 = (float*)(wb + (size_t)N_PAD * K_DIM);
  float* w2 = x2 + M_DIM;

  cvt_rows<<<M_DIM / 4, 256, 0, stream>>>(x, xb, x2, M_DIM);
  cvt_rows<<<N_PAD / 4, 256, 0, stream>>>(w, wb, w2, N_DIM);
  gemm_ep<<<(M_DIM / BM) * (N_PAD / BN), 512, 0, stream>>>(xb, wb, x2, w2, out);
}